// Round 1
// baseline (256.554 us; speedup 1.0000x reference)
//
#include <hip/hip_runtime.h>

#define NB 15

// ws layout (floats): [0]=focal_sum, [1]=cp_sum, [2..16]=per-bin sum(t - p)

__global__ __launch_bounds__(256) void fcl_main(
    const float* __restrict__ p_hat,
    const float* __restrict__ u_hat,
    const int*   __restrict__ targets,
    float* __restrict__ ws,
    int n4, int n)
{
    // 8 replicated histogram copies (one per half-wave) to cut ds_add_f32
    // same-address serialization to ~2-way. Stride 16 keeps copies bank-spread.
    __shared__ float sbins[8][16];
    for (int i = threadIdx.x; i < 8 * 16; i += blockDim.x)
        ((float*)sbins)[i] = 0.0f;
    __syncthreads();

    const int copy = threadIdx.x >> 5;   // 0..7

    float facc = 0.0f;
    float cacc = 0.0f;

    const float4* p4 = (const float4*)p_hat;
    const float4* u4 = (const float4*)u_hat;
    const int4*   t4 = (const int4*)targets;

    const int stride = gridDim.x * blockDim.x;
    for (int i = blockIdx.x * blockDim.x + threadIdx.x; i < n4; i += stride) {
        float4 p = p4[i];
        float4 u = u4[i];
        int4   t = t4[i];
        #pragma unroll
        for (int k = 0; k < 4; ++k) {
            float pk = (&p.x)[k];
            float uk = (&u.x)[k];
            int   tk = (&t.x)[k];
            bool pos = (tk == 1);

            // focal: -alpha * (1-pt)^2 * log(pt + 1e-12)
            float pt    = pos ? pk : 1.0f - pk;
            float alpha = pos ? 1.0f : 2.0f;
            float om    = 1.0f - pt;
            facc -= alpha * om * om * __logf(pt + 1e-12f);

            // calibration penalty
            float pen;
            if (pos) { pen = (pk < 0.7f) ? uk * uk : 0.0f; }
            else     { float w = 1.0f - uk; pen = (pk > 0.7f) ? w * w : 0.0f; }
            cacc += pen;

            // ECE histogram: bin = clip(ceil(p*15)-1, 0, 14); accumulate (t - p)
            int b = (int)ceilf(pk * 15.0f) - 1;
            b = max(0, min(NB - 1, b));
            float tf = pos ? 1.0f : 0.0f;
            atomicAdd(&sbins[copy][b], tf - pk);
        }
    }

    // scalar tail (n not multiple of 4) — handled by one global thread
    if (blockIdx.x == 0 && threadIdx.x == 0) {
        for (int i = n4 * 4; i < n; ++i) {
            float pk = p_hat[i];
            float uk = u_hat[i];
            bool pos = (targets[i] == 1);
            float pt    = pos ? pk : 1.0f - pk;
            float alpha = pos ? 1.0f : 2.0f;
            float om    = 1.0f - pt;
            facc -= alpha * om * om * __logf(pt + 1e-12f);
            float pen;
            if (pos) { pen = (pk < 0.7f) ? uk * uk : 0.0f; }
            else     { float w = 1.0f - uk; pen = (pk > 0.7f) ? w * w : 0.0f; }
            cacc += pen;
            int b = (int)ceilf(pk * 15.0f) - 1;
            b = max(0, min(NB - 1, b));
            atomicAdd(&sbins[copy][b], (pos ? 1.0f : 0.0f) - pk);
        }
    }

    // wave-64 shuffle reduction of focal / cp
    #pragma unroll
    for (int off = 32; off > 0; off >>= 1) {
        facc += __shfl_down(facc, off, 64);
        cacc += __shfl_down(cacc, off, 64);
    }

    __shared__ float wsum[2][4];
    const int wave = threadIdx.x >> 6;
    const int lane = threadIdx.x & 63;
    if (lane == 0) { wsum[0][wave] = facc; wsum[1][wave] = cacc; }
    __syncthreads();   // also fences all sbins LDS atomics

    if (threadIdx.x == 0) {
        float f = wsum[0][0] + wsum[0][1] + wsum[0][2] + wsum[0][3];
        float c = wsum[1][0] + wsum[1][1] + wsum[1][2] + wsum[1][3];
        atomicAdd(&ws[0], f);
        atomicAdd(&ws[1], c);
    }
    if (threadIdx.x < NB) {
        float s = 0.0f;
        #pragma unroll
        for (int c = 0; c < 8; ++c) s += sbins[c][threadIdx.x];
        atomicAdd(&ws[2 + threadIdx.x], s);
    }
}

__global__ void fcl_final(const float* __restrict__ ws,
                          float* __restrict__ out, float inv_n)
{
    if (threadIdx.x == 0) {
        float e = 0.0f;
        #pragma unroll
        for (int b = 0; b < NB; ++b) e += fabsf(ws[2 + b]);
        out[0] = (ws[0] + 6.0f * ws[1] + 5.0f * e) * inv_n;
    }
}

extern "C" void kernel_launch(void* const* d_in, const int* in_sizes, int n_in,
                              void* d_out, int out_size, void* d_ws, size_t ws_size,
                              hipStream_t stream) {
    const float* p = (const float*)d_in[0];
    const float* u = (const float*)d_in[1];
    const int*   t = (const int*)d_in[2];
    float* out = (float*)d_out;
    float* ws  = (float*)d_ws;

    const int n  = in_sizes[0];
    const int n4 = n / 4;

    hipMemsetAsync(ws, 0, (2 + NB) * sizeof(float), stream);

    const int block = 256;
    const int grid  = 2048;   // 8 blocks/CU on 256 CUs; ~8 float4 per thread
    fcl_main<<<grid, block, 0, stream>>>(p, u, t, ws, n4, n);
    fcl_final<<<1, 64, 0, stream>>>(ws, out, 1.0f / (float)n);
}

// Round 2
// 204.985 us; speedup vs baseline: 1.2516x; 1.2516x over previous
//
#include <hip/hip_runtime.h>

#define NB 15
#define NV 17          // focal, cp, 15 bins
#define GRID 1024
#define BLOCK 256

// partials layout in ws: partials[j * GRID + block], j in [0,17)
// j=0: focal sum, j=1: cp sum, j=2..16: per-bin sum(t - p)

__device__ __forceinline__ void process_elem(float pk, float uk, int tk,
                                             float& facc, float& cacc,
                                             float* bins)
{
    bool pos = (tk == 1);

    // focal: -alpha * (1-pt)^2 * log(pt + 1e-12)
    float pt    = pos ? pk : 1.0f - pk;
    float alpha = pos ? 1.0f : 2.0f;
    float om    = 1.0f - pt;
    facc -= alpha * om * om * __logf(pt + 1e-12f);

    // calibration penalty
    float w   = 1.0f - uk;
    float pen = pos ? ((pk < 0.7f) ? uk * uk : 0.0f)
                    : ((pk > 0.7f) ? w * w : 0.0f);
    cacc += pen;

    // ECE histogram into REGISTER bins (no LDS atomics)
    int b = (int)ceilf(pk * 15.0f) - 1;
    b = (b < 0) ? 0 : ((b > NB - 1) ? NB - 1 : b);
    float v = (pos ? 1.0f : 0.0f) - pk;
    #pragma unroll
    for (int j = 0; j < NB; ++j)
        bins[j] += (b == j) ? v : 0.0f;
}

__global__ __launch_bounds__(BLOCK) void fcl_main(
    const float* __restrict__ p_hat,
    const float* __restrict__ u_hat,
    const int*   __restrict__ targets,
    float* __restrict__ partials,
    int n4, int n)
{
    float bins[NB];
    #pragma unroll
    for (int j = 0; j < NB; ++j) bins[j] = 0.0f;
    float facc = 0.0f, cacc = 0.0f;

    const float4* __restrict__ p4 = (const float4*)p_hat;
    const float4* __restrict__ u4 = (const float4*)u_hat;
    const int4*   __restrict__ t4 = (const int4*)targets;

    const int stride = gridDim.x * blockDim.x;
    int i = blockIdx.x * blockDim.x + threadIdx.x;

    // 2x unrolled grid-stride: keeps 6 vector loads in flight
    for (; i + stride < n4; i += 2 * stride) {
        float4 p0 = p4[i];          float4 p1 = p4[i + stride];
        float4 u0 = u4[i];          float4 u1 = u4[i + stride];
        int4   t0 = t4[i];          int4   t1 = t4[i + stride];
        #pragma unroll
        for (int k = 0; k < 4; ++k)
            process_elem((&p0.x)[k], (&u0.x)[k], (&t0.x)[k], facc, cacc, bins);
        #pragma unroll
        for (int k = 0; k < 4; ++k)
            process_elem((&p1.x)[k], (&u1.x)[k], (&t1.x)[k], facc, cacc, bins);
    }
    if (i < n4) {
        float4 p0 = p4[i]; float4 u0 = u4[i]; int4 t0 = t4[i];
        #pragma unroll
        for (int k = 0; k < 4; ++k)
            process_elem((&p0.x)[k], (&u0.x)[k], (&t0.x)[k], facc, cacc, bins);
    }

    // scalar tail (n not multiple of 4)
    if (blockIdx.x == 0 && threadIdx.x == 0) {
        for (int j = n4 * 4; j < n; ++j)
            process_elem(p_hat[j], u_hat[j], targets[j], facc, cacc, bins);
    }

    // wave-64 shuffle reduction of all 17 values
    float vals[NV];
    vals[0] = facc; vals[1] = cacc;
    #pragma unroll
    for (int j = 0; j < NB; ++j) vals[2 + j] = bins[j];

    #pragma unroll
    for (int off = 32; off > 0; off >>= 1) {
        #pragma unroll
        for (int j = 0; j < NV; ++j)
            vals[j] += __shfl_down(vals[j], off, 64);
    }

    __shared__ float lds[BLOCK / 64][NV];
    const int wave = threadIdx.x >> 6;
    const int lane = threadIdx.x & 63;
    if (lane == 0) {
        #pragma unroll
        for (int j = 0; j < NV; ++j) lds[wave][j] = vals[j];
    }
    __syncthreads();

    if (threadIdx.x < NV) {
        float s = 0.0f;
        #pragma unroll
        for (int w = 0; w < BLOCK / 64; ++w) s += lds[w][threadIdx.x];
        partials[threadIdx.x * gridDim.x + blockIdx.x] = s;
    }
}

__global__ __launch_bounds__(1024) void fcl_final(
    const float* __restrict__ partials,
    float* __restrict__ out, float inv_n, int grid)
{
    const int t = threadIdx.x;   // 1024 threads == grid size
    float v[NV];
    #pragma unroll
    for (int j = 0; j < NV; ++j) v[j] = partials[j * grid + t];

    #pragma unroll
    for (int off = 32; off > 0; off >>= 1) {
        #pragma unroll
        for (int j = 0; j < NV; ++j)
            v[j] += __shfl_down(v[j], off, 64);
    }

    __shared__ float lds[16][NV];
    const int wave = t >> 6;
    const int lane = t & 63;
    if (lane == 0) {
        #pragma unroll
        for (int j = 0; j < NV; ++j) lds[wave][j] = v[j];
    }
    __syncthreads();

    if (t == 0) {
        float s[NV];
        #pragma unroll
        for (int j = 0; j < NV; ++j) s[j] = 0.0f;
        for (int w = 0; w < 16; ++w)
            #pragma unroll
            for (int j = 0; j < NV; ++j) s[j] += lds[w][j];
        float e = 0.0f;
        #pragma unroll
        for (int b = 0; b < NB; ++b) e += fabsf(s[2 + b]);
        out[0] = (s[0] + 6.0f * s[1] + 5.0f * e) * inv_n;
    }
}

extern "C" void kernel_launch(void* const* d_in, const int* in_sizes, int n_in,
                              void* d_out, int out_size, void* d_ws, size_t ws_size,
                              hipStream_t stream) {
    const float* p = (const float*)d_in[0];
    const float* u = (const float*)d_in[1];
    const int*   t = (const int*)d_in[2];
    float* out = (float*)d_out;
    float* ws  = (float*)d_ws;

    const int n  = in_sizes[0];
    const int n4 = n / 4;

    fcl_main<<<GRID, BLOCK, 0, stream>>>(p, u, t, ws, n4, n);
    fcl_final<<<1, 1024, 0, stream>>>(ws, out, 1.0f / (float)n, GRID);
}